// Round 6
// baseline (137.575 us; speedup 1.0000x reference)
//
#include <hip/hip_runtime.h>

#define MDIM 4096
#define KDIM 2048
#define UDIM 1024
#define CMOFF (MDIM * UDIM)
#define NK 64  // KDIM / 32
#define THREADS 512

typedef __bf16 bfrag __attribute__((ext_vector_type(8)));
typedef float f32x4 __attribute__((ext_vector_type(4)));

#define GLDS(gsrc, ldst)                                                                  \
  __builtin_amdgcn_global_load_lds((const __attribute__((address_space(1))) void*)(gsrc), \
                                   (__attribute__((address_space(3))) void*)(ldst), 16, 0, 0)

// asm-pinned ds_read_b128: cannot be sunk/merged/eliminated by the scheduler.
#define DSR(dst, addr, OFF) \
  asm volatile("ds_read_b128 %0, %1 offset:" OFF : "=v"(dst) : "v"(addr))

__device__ __forceinline__ unsigned short f2bf(float x) {
  unsigned int u = __float_as_uint(x);
  unsigned int r = (u + 0x7fffu + ((u >> 16) & 1u)) >> 16;
  return (unsigned short)r;
}

__device__ __forceinline__ float fast_sigmoid(float x) { return 1.f / (1.f + __expf(-x)); }

__device__ __forceinline__ float fast_tanh(float x) {
  float ax = fabsf(x);
  float e = __expf(-2.f * ax);
  float r = (1.f - e) / (1.f + e);
  return copysignf(r, x);
}

// Build A = [hidden | inputs] as bf16, row-major [4096][2048]
__global__ void pack_x(const float* __restrict__ hidden, const float* __restrict__ inputs,
                       unsigned short* __restrict__ A) {
  int t = blockIdx.x * blockDim.x + threadIdx.x;
  int e = t * 4;
  int m = e >> 11;
  int c = e & 2047;
  const float* src = (c < 1024) ? (hidden + m * 1024 + c) : (inputs + m * 1024 + (c - 1024));
  float4 v = *(const float4*)src;
  ushort4 o;
  o.x = f2bf(v.x);
  o.y = f2bf(v.y);
  o.z = f2bf(v.z);
  o.w = f2bf(v.w);
  *(ushort4*)(A + e) = o;
}

// Transpose each W_g [2048][1024] f32 -> Wt rows [g*1024+u][k] bf16 ([4096][2048])
__global__ void pack_w(const float* __restrict__ Wf, const float* __restrict__ Wi,
                       const float* __restrict__ Wc, const float* __restrict__ Wo,
                       unsigned short* __restrict__ Wt) {
  __shared__ float tile[32][33];
  const int k0 = blockIdx.x * 32;
  const int u0 = blockIdx.y * 32;
  const int g = blockIdx.z;
  const float* W = (g == 0) ? Wf : (g == 1) ? Wi : (g == 2) ? Wc : Wo;
  const int t = threadIdx.x;
  {
    int kk = t >> 3, uu = (t & 7) * 4;
    float4 v = *(const float4*)(W + (k0 + kk) * UDIM + u0 + uu);
    tile[kk][uu + 0] = v.x;
    tile[kk][uu + 1] = v.y;
    tile[kk][uu + 2] = v.z;
    tile[kk][uu + 3] = v.w;
  }
  __syncthreads();
  {
    int ur = t >> 3, k4 = (t & 7) * 4;
    ushort4 o;
    o.x = f2bf(tile[k4 + 0][ur]);
    o.y = f2bf(tile[k4 + 1][ur]);
    o.z = f2bf(tile[k4 + 2][ur]);
    o.w = f2bf(tile[k4 + 3][ur]);
    *(ushort4*)(Wt + (size_t)(g * UDIM + u0 + ur) * KDIM + k0 + k4) = o;
  }
}

// Fused 4-gate GEMM + LSTM epilogue, 16x16x32 MFMA, asm-pinned 1-tile-deep pipeline.
// 256(M) x 256(N) tile, BK=32, 4-deep LDS ring, 1 barrier/tile, vmcnt(4)/tile.
// Ring invariant: end-of-tile-T vmcnt(4)+barrier guarantees stages <= T+2 landed
// (only stage T+3's 4 loads may remain in flight), so at tile-T start rings T and
// T+1 are both valid: tile T's fragments were asm-preloaded during T-1, and tile
// T+1's fragments are asm-preloaded during T (overlapping T's MFMA cluster, no
// lgkm wait in between). ds_read latency/throughput hides under the MFMA pipe.
__global__ __launch_bounds__(THREADS, 2) void lstm_gemm(
    const unsigned short* __restrict__ A, const unsigned short* __restrict__ Wt,
    const float* __restrict__ bf_, const float* __restrict__ bi_,
    const float* __restrict__ bc_, const float* __restrict__ bo_,
    const float* __restrict__ cell, float* __restrict__ out) {
  extern __shared__ __bf16 lds[];  // 4 rings x (A 8192 + B 8192 elems) = 128 KiB

  const int tid = threadIdx.x;
  const int lane = tid & 63;
  const int wid = tid >> 6;
  const int wr = wid >> 2;   // M-half of block
  const int wc = wid & 3;    // N quarter
  const int lrow = lane & 15;
  const int gb = lane >> 4;  // k-granule (16B) index within 64B row

  // bijective XCD swizzle over exactly 256 workgroups (1 per CU)
  const int wg = blockIdx.x;
  const int swz = (wg & 7) * 32 + (wg >> 3);
  const int m0 = (swz >> 4) * 256;
  const int bn = swz & 15;  // 64-unit block

  // ---- staging source pointers (inverse-swizzled global addresses) ----
  // LDS linear granule G holds: row = G>>2, source-granule = (G&3) ^ ((row>>1)&3)
  const int G0 = tid, G1 = THREADS + tid;
  const int ar0 = G0 >> 2, ar1 = G1 >> 2;
  const unsigned short* aS0 =
      A + (size_t)(m0 + ar0) * KDIM + (((G0 & 3) ^ ((ar0 >> 1) & 3)) * 8);
  const unsigned short* aS1 =
      A + (size_t)(m0 + ar1) * KDIM + (((G1 & 3) ^ ((ar1 >> 1) & 3)) * 8);
  // B LDS row n in [0,256): gate g=(n>>4)&3, unit u = bn*64 + (n>>6)*16 + (n&15)
  const int nr0 = G0 >> 2, nr1 = G1 >> 2;
  const int u_0 = bn * 64 + ((nr0 >> 6) << 4) + (nr0 & 15);
  const int u_1 = bn * 64 + ((nr1 >> 6) << 4) + (nr1 & 15);
  const int g_0 = (nr0 >> 4) & 3;
  const int g_1 = (nr1 >> 4) & 3;
  const unsigned short* bS0 =
      Wt + (size_t)(g_0 * UDIM + u_0) * KDIM + (((G0 & 3) ^ ((nr0 >> 1) & 3)) * 8);
  const unsigned short* bS1 =
      Wt + (size_t)(g_1 * UDIM + u_1) * KDIM + (((G1 & 3) ^ ((nr1 >> 1) & 3)) * 8);

  // ---- fragment base byte addresses (LDS AS3), swizzled; per-mi/nf deltas are
  // compile-time: +16 rows => +1024 bytes, swizzle term invariant (R>>1)&3. ----
  const int R0 = wr * 128 + lrow;
  const int aoff0 = R0 * 32 + ((gb ^ ((R0 >> 1) & 3)) * 8);
  const int n0 = wc * 64 + lrow;
  const int boff0 = 8192 + n0 * 32 + ((gb ^ ((n0 >> 1) & 3)) * 8);
  const unsigned ldsb = (unsigned)(size_t)(__attribute__((address_space(3))) void*)lds;
  const unsigned aB = ldsb + (unsigned)aoff0 * 2u;
  const unsigned bB = ldsb + (unsigned)boff0 * 2u;

  f32x4 acc[8][4];
#pragma unroll
  for (int mi = 0; mi < 8; ++mi)
#pragma unroll
    for (int nf = 0; nf < 4; ++nf) acc[mi][nf] = (f32x4){0.f, 0.f, 0.f, 0.f};

#define STAGE_A(T, SR)                        \
  do {                                        \
    __bf16* dst_ = lds + (SR) * 16384;        \
    GLDS(aS0 + (T) * 32, dst_ + G0 * 8);      \
    GLDS(aS1 + (T) * 32, dst_ + G1 * 8);      \
  } while (0)
#define STAGE_B(T, SR)                        \
  do {                                        \
    __bf16* dst_ = lds + (SR) * 16384 + 8192; \
    GLDS(bS0 + (T) * 32, dst_ + G0 * 8);      \
    GLDS(bS1 + (T) * 32, dst_ + G1 * 8);      \
  } while (0)

#define VM4 asm volatile("s_waitcnt vmcnt(4)" ::: "memory")
#define VM0 asm volatile("s_waitcnt vmcnt(0)" ::: "memory")

#define PRELOAD(PRNG, NA, NB)                      \
  do {                                             \
    const unsigned vA_ = aB + (PRNG)*32768u;       \
    const unsigned vB_ = bB + (PRNG)*32768u;       \
    DSR(NA[0], vA_, "0");                          \
    DSR(NA[1], vA_, "1024");                       \
    DSR(NA[2], vA_, "2048");                       \
    DSR(NA[3], vA_, "3072");                       \
    DSR(NA[4], vA_, "4096");                       \
    DSR(NA[5], vA_, "5120");                       \
    DSR(NA[6], vA_, "6144");                       \
    DSR(NA[7], vA_, "7168");                       \
    DSR(NB[0], vB_, "0");                          \
    DSR(NB[1], vB_, "1024");                       \
    DSR(NB[2], vB_, "2048");                       \
    DSR(NB[3], vB_, "3072");                       \
  } while (0)

  // fragment double buffers (asm outputs -> cannot be coalesced away)
  bfrag Fa0[8], Fb0[4], Fa1[8], Fb1[4];

  // prologue: stage rings 0,1,2; vmcnt(4) -> rings 0,1 landed; preload tile 0
  STAGE_A(0, 0);
  STAGE_B(0, 0);
  STAGE_A(1, 1);
  STAGE_B(1, 1);
  STAGE_A(2, 2);
  STAGE_B(2, 2);
  VM4;
  __builtin_amdgcn_s_barrier();
  PRELOAD(0, Fa0, Fb0);

#define TILE_BODY(T, PRNG, SRNG, DO_STAGE, DO_PRELOAD, CA, CB, NA, NB, WAITCODE)          \
  do {                                                                                    \
    asm volatile("s_waitcnt lgkmcnt(0)" ::: "memory");                                    \
    __builtin_amdgcn_sched_barrier(0);                                                    \
    if (DO_STAGE) STAGE_A((T) + 3, SRNG);                                                 \
    if (DO_PRELOAD) PRELOAD(PRNG, NA, NB);                                                \
    if (DO_STAGE) STAGE_B((T) + 3, SRNG);                                                 \
    __builtin_amdgcn_s_setprio(1);                                                        \
    _Pragma("unroll") for (int mi = 0; mi < 8; ++mi)                                      \
        _Pragma("unroll") for (int nf = 0; nf < 4; ++nf) acc[mi][nf] =                    \
            __builtin_amdgcn_mfma_f32_16x16x32_bf16(CA[mi], CB[nf], acc[mi][nf], 0, 0, 0); \
    __builtin_amdgcn_s_setprio(0);                                                        \
    WAITCODE;                                                                             \
    __builtin_amdgcn_s_barrier();                                                         \
  } while (0)

  for (int t = 0; t < NK - 4; t += 4) {  // tiles 0..59 (t multiple of 4)
    TILE_BODY(t + 0, 1, 3, 1, 1, Fa0, Fb0, Fa1, Fb1, VM4);
    TILE_BODY(t + 1, 2, 0, 1, 1, Fa1, Fb1, Fa0, Fb0, VM4);
    TILE_BODY(t + 2, 3, 1, 1, 1, Fa0, Fb0, Fa1, Fb1, VM4);
    TILE_BODY(t + 3, 0, 2, 1, 1, Fa1, Fb1, Fa0, Fb0, VM4);
  }
  TILE_BODY(60, 1, 3, 1, 1, Fa0, Fb0, Fa1, Fb1, VM4);  // stages tile 63 (ring 3)
  TILE_BODY(61, 2, 0, 0, 1, Fa1, Fb1, Fa0, Fb0, VM0);  // preload 62; drain all
  TILE_BODY(62, 3, 0, 0, 1, Fa0, Fb0, Fa1, Fb1, );     // preload 63
  TILE_BODY(63, 0, 0, 0, 0, Fa1, Fb1, Fa0, Fb0, );

  // ---- epilogue: per lane, 4 nf-fragments = the 4 gates of one unit u ----
  const int u = bn * 64 + wc * 16 + lrow;
  const float fb = bf_[u], ib = bi_[u], cb = bc_[u], ob = bo_[u];
  const int rbase = m0 + wr * 128 + (lane >> 4) * 4;
#pragma unroll
  for (int mi = 0; mi < 8; ++mi) {
#pragma unroll
    for (int j = 0; j < 4; ++j) {
      const int m = rbase + mi * 16 + j;
      float pf = acc[mi][0][j] + fb;
      float pi = acc[mi][1][j] + ib;
      float pc = acc[mi][2][j] + cb;
      float po = acc[mi][3][j] + ob;
      float fg = fast_sigmoid(pf);
      float ig = fast_sigmoid(pi);
      float cc = fast_tanh(pc);
      float og = fast_sigmoid(po);
      float cold = cell[(size_t)m * UDIM + u];
      float cnew = fg * cold + ig * cc;
      out[(size_t)m * UDIM + u] = og * fast_tanh(cnew);
      out[CMOFF + (size_t)m * UDIM + u] = cnew;
    }
  }
}

extern "C" void kernel_launch(void* const* d_in, const int* in_sizes, int n_in,
                              void* d_out, int out_size, void* d_ws, size_t ws_size,
                              hipStream_t stream) {
  const float* inputs = (const float*)d_in[0];
  const float* hidden = (const float*)d_in[1];
  const float* cell = (const float*)d_in[2];
  const float* Wf = (const float*)d_in[3];
  const float* bf = (const float*)d_in[4];
  const float* Wi = (const float*)d_in[5];
  const float* bi = (const float*)d_in[6];
  const float* Wc = (const float*)d_in[7];
  const float* bc = (const float*)d_in[8];
  const float* Wo = (const float*)d_in[9];
  const float* bo = (const float*)d_in[10];
  float* out = (float*)d_out;

  unsigned short* Abf = (unsigned short*)d_ws;     // [4096][2048] bf16 = 16 MB
  unsigned short* Wt = Abf + (size_t)MDIM * KDIM;  // [4096][2048] bf16 = 16 MB

  pack_x<<<(MDIM * KDIM / 4) / 256, 256, 0, stream>>>(hidden, inputs, Abf);
  pack_w<<<dim3(KDIM / 32, UDIM / 32, 4), 256, 0, stream>>>(Wf, Wi, Wc, Wo, Wt);
  lstm_gemm<<<dim3(256), dim3(THREADS), 131072, stream>>>(Abf, Wt, bf, bi, bc, bo, cell, out);
}

// Round 7
// 89.884 us; speedup vs baseline: 1.5306x; 1.5306x over previous
//
#include <hip/hip_runtime.h>

#define MDIM 4096
#define KDIM 2048
#define UDIM 1024
#define CMOFF (MDIM * UDIM)
#define NK 64  // KDIM / 32
#define THREADS 512

typedef __bf16 bfrag __attribute__((ext_vector_type(8)));
typedef float f32x4 __attribute__((ext_vector_type(4)));

#define GLDS(gsrc, ldst)                                                                  \
  __builtin_amdgcn_global_load_lds((const __attribute__((address_space(1))) void*)(gsrc), \
                                   (__attribute__((address_space(3))) void*)(ldst), 16, 0, 0)

__device__ __forceinline__ unsigned short f2bf(float x) {
  unsigned int u = __float_as_uint(x);
  unsigned int r = (u + 0x7fffu + ((u >> 16) & 1u)) >> 16;
  return (unsigned short)r;
}

__device__ __forceinline__ float fast_sigmoid(float x) { return 1.f / (1.f + __expf(-x)); }

__device__ __forceinline__ float fast_tanh(float x) {
  float ax = fabsf(x);
  float e = __expf(-2.f * ax);
  float r = (1.f - e) / (1.f + e);
  return copysignf(r, x);
}

// Build A = [hidden | inputs] as bf16, row-major [4096][2048]
__global__ void pack_x(const float* __restrict__ hidden, const float* __restrict__ inputs,
                       unsigned short* __restrict__ A) {
  int t = blockIdx.x * blockDim.x + threadIdx.x;
  int e = t * 4;
  int m = e >> 11;
  int c = e & 2047;
  const float* src = (c < 1024) ? (hidden + m * 1024 + c) : (inputs + m * 1024 + (c - 1024));
  float4 v = *(const float4*)src;
  ushort4 o;
  o.x = f2bf(v.x);
  o.y = f2bf(v.y);
  o.z = f2bf(v.z);
  o.w = f2bf(v.w);
  *(ushort4*)(A + e) = o;
}

// Transpose each W_g [2048][1024] f32 -> Wt rows [g*1024+u][k] bf16 ([4096][2048])
__global__ void pack_w(const float* __restrict__ Wf, const float* __restrict__ Wi,
                       const float* __restrict__ Wc, const float* __restrict__ Wo,
                       unsigned short* __restrict__ Wt) {
  __shared__ float tile[32][33];
  const int k0 = blockIdx.x * 32;
  const int u0 = blockIdx.y * 32;
  const int g = blockIdx.z;
  const float* W = (g == 0) ? Wf : (g == 1) ? Wi : (g == 2) ? Wc : Wo;
  const int t = threadIdx.x;
  {
    int kk = t >> 3, uu = (t & 7) * 4;
    float4 v = *(const float4*)(W + (k0 + kk) * UDIM + u0 + uu);
    tile[kk][uu + 0] = v.x;
    tile[kk][uu + 1] = v.y;
    tile[kk][uu + 2] = v.z;
    tile[kk][uu + 3] = v.w;
  }
  __syncthreads();
  {
    int ur = t >> 3, k4 = (t & 7) * 4;
    ushort4 o;
    o.x = f2bf(tile[k4 + 0][ur]);
    o.y = f2bf(tile[k4 + 1][ur]);
    o.z = f2bf(tile[k4 + 2][ur]);
    o.w = f2bf(tile[k4 + 3][ur]);
    *(ushort4*)(Wt + (size_t)(g * UDIM + u0 + ur) * KDIM + k0 + k4) = o;
  }
}

// Fused 4-gate GEMM + LSTM epilogue, 16x16x32 MFMA.
// 256(M) x 256(N: 64 units x 4 gates) tile, BK=32, 4-deep LDS K-tile ring,
// ONE barrier + ONE counted vmcnt per tile (at tile start), granule-XOR swizzle.
// Correctness (per-tile, ring R=T&3):
//  (i) reads of ring T valid: each wave's VM8 at tile-T start bounds its own
//      outstanding GLDS to stages T+1,T+2 (8 ops) => its stage-T ops landed;
//      the barrier after VM8 makes ALL waves' stage-T data visible.
// (ii) STAGE(T+3) (ring (T-1)&3) issued after barrier(T); every ds_read of
//      ring (T-1) was consumed by an lgkm-waited MFMA before its wave reached
//      barrier(T) => no overwrite race. Mid-tile barrier removed: cluster-1
//      MFMAs overlap A2 ds_reads + STAGE_B issue; waves desync within a tile
//      so LDS and MFMA pipes both stay fed.
__global__ __launch_bounds__(THREADS, 2) void lstm_gemm(
    const unsigned short* __restrict__ A, const unsigned short* __restrict__ Wt,
    const float* __restrict__ bf_, const float* __restrict__ bi_,
    const float* __restrict__ bc_, const float* __restrict__ bo_,
    const float* __restrict__ cell, float* __restrict__ out) {
  extern __shared__ __bf16 lds[];  // 4 rings x (A 8192 + B 8192 elems) = 128 KiB

  const int tid = threadIdx.x;
  const int lane = tid & 63;
  const int wid = tid >> 6;
  const int wr = wid >> 2;   // M-half of block
  const int wc = wid & 3;    // N quarter
  const int lrow = lane & 15;
  const int gb = lane >> 4;  // k-granule (16B) index within 64B row

  // bijective XCD swizzle over exactly 256 workgroups (1 per CU)
  const int wg = blockIdx.x;
  const int swz = (wg & 7) * 32 + (wg >> 3);
  const int m0 = (swz >> 4) * 256;
  const int bn = swz & 15;  // 64-unit block

  // ---- staging source pointers (inverse-swizzled global addresses) ----
  // LDS linear granule G holds: row = G>>2, source-granule = (G&3) ^ ((row>>1)&3)
  const int G0 = tid, G1 = THREADS + tid;
  const int ar0 = G0 >> 2, ar1 = G1 >> 2;
  const unsigned short* aS0 =
      A + (size_t)(m0 + ar0) * KDIM + (((G0 & 3) ^ ((ar0 >> 1) & 3)) * 8);
  const unsigned short* aS1 =
      A + (size_t)(m0 + ar1) * KDIM + (((G1 & 3) ^ ((ar1 >> 1) & 3)) * 8);
  // B LDS row n in [0,256): gate g=(n>>4)&3, unit u = bn*64 + (n>>6)*16 + (n&15)
  const int nr0 = G0 >> 2, nr1 = G1 >> 2;
  const int u_0 = bn * 64 + ((nr0 >> 6) << 4) + (nr0 & 15);
  const int u_1 = bn * 64 + ((nr1 >> 6) << 4) + (nr1 & 15);
  const int g_0 = (nr0 >> 4) & 3;
  const int g_1 = (nr1 >> 4) & 3;
  const unsigned short* bS0 =
      Wt + (size_t)(g_0 * UDIM + u_0) * KDIM + (((G0 & 3) ^ ((nr0 >> 1) & 3)) * 8);
  const unsigned short* bS1 =
      Wt + (size_t)(g_1 * UDIM + u_1) * KDIM + (((G1 & 3) ^ ((nr1 >> 1) & 3)) * 8);

  // ---- fragment read offsets (elems, without ring base), swizzled ----
  int aoff[8];
#pragma unroll
  for (int mi = 0; mi < 8; ++mi) {
    const int R = wr * 128 + mi * 16 + lrow;
    aoff[mi] = R * 32 + ((gb ^ ((R >> 1) & 3)) * 8);
  }
  int boff[4];
#pragma unroll
  for (int nf = 0; nf < 4; ++nf) {
    const int n = wc * 64 + nf * 16 + lrow;
    boff[nf] = 8192 + n * 32 + ((gb ^ ((n >> 1) & 3)) * 8);
  }

  f32x4 acc[8][4];
#pragma unroll
  for (int mi = 0; mi < 8; ++mi)
#pragma unroll
    for (int nf = 0; nf < 4; ++nf) acc[mi][nf] = (f32x4){0.f, 0.f, 0.f, 0.f};

#define STAGE_A(T, SR)                        \
  do {                                        \
    __bf16* dst_ = lds + (SR) * 16384;        \
    GLDS(aS0 + (T) * 32, dst_ + G0 * 8);      \
    GLDS(aS1 + (T) * 32, dst_ + G1 * 8);      \
  } while (0)
#define STAGE_B(T, SR)                        \
  do {                                        \
    __bf16* dst_ = lds + (SR) * 16384 + 8192; \
    GLDS(bS0 + (T) * 32, dst_ + G0 * 8);      \
    GLDS(bS1 + (T) * 32, dst_ + G1 * 8);      \
  } while (0)

#define VM8 asm volatile("s_waitcnt vmcnt(8)" ::: "memory")
#define VM4 asm volatile("s_waitcnt vmcnt(4)" ::: "memory")
#define VM0 asm volatile("s_waitcnt vmcnt(0)" ::: "memory")

  // prologue: rings 0,1,2 in flight (12 GLDS/wave outstanding)
  STAGE_A(0, 0);
  STAGE_B(0, 0);
  STAGE_A(1, 1);
  STAGE_B(1, 1);
  STAGE_A(2, 2);
  STAGE_B(2, 2);

#define TILE_BODY(T, R, SR, DO_STAGE, WAITCODE)                                            \
  do {                                                                                     \
    WAITCODE;                                                                              \
    __builtin_amdgcn_s_barrier();                                                          \
    __bf16* ldsr_ = lds + (R) * 16384;                                                     \
    bfrag Am[4], Bm[4];                                                                    \
    _Pragma("unroll") for (int mi = 0; mi < 4; ++mi) Am[mi] =                              \
        *(const bfrag*)(ldsr_ + aoff[mi]);                                                 \
    _Pragma("unroll") for (int nf = 0; nf < 4; ++nf) Bm[nf] =                              \
        *(const bfrag*)(ldsr_ + boff[nf]);                                                 \
    if (DO_STAGE) STAGE_A((T) + 3, SR);                                                    \
    __builtin_amdgcn_s_setprio(1);                                                         \
    _Pragma("unroll") for (int mi = 0; mi < 4; ++mi)                                       \
        _Pragma("unroll") for (int nf = 0; nf < 4; ++nf) acc[mi][nf] =                     \
            __builtin_amdgcn_mfma_f32_16x16x32_bf16(Am[mi], Bm[nf], acc[mi][nf], 0, 0, 0); \
    __builtin_amdgcn_s_setprio(0);                                                         \
    bfrag A2[4];                                                                           \
    _Pragma("unroll") for (int mi = 0; mi < 4; ++mi) A2[mi] =                              \
        *(const bfrag*)(ldsr_ + aoff[4 + mi]);                                             \
    if (DO_STAGE) STAGE_B((T) + 3, SR);                                                    \
    __builtin_amdgcn_s_setprio(1);                                                         \
    _Pragma("unroll") for (int mi = 0; mi < 4; ++mi)                                       \
        _Pragma("unroll") for (int nf = 0; nf < 4; ++nf) acc[4 + mi][nf] =                 \
            __builtin_amdgcn_mfma_f32_16x16x32_bf16(A2[mi], Bm[nf], acc[4 + mi][nf], 0, 0, 0); \
    __builtin_amdgcn_s_setprio(0);                                                         \
  } while (0)

  for (int t = 0; t < NK - 4; t += 4) {  // tiles 0..59, stages 3..62
    TILE_BODY(t + 0, 0, 3, 1, VM8);
    TILE_BODY(t + 1, 1, 0, 1, VM8);
    TILE_BODY(t + 2, 2, 1, 1, VM8);
    TILE_BODY(t + 3, 3, 2, 1, VM8);
  }
  TILE_BODY(NK - 4, 0, 3, 1, VM8);  // tile 60, stages tile 63 into ring 3
  TILE_BODY(NK - 3, 1, 0, 0, VM8);  // tile 61: outstanding 61,62,63 -> need 61: <=8
  TILE_BODY(NK - 2, 2, 0, 0, VM4);  // tile 62: outstanding 62,63 -> need 62: <=4
  TILE_BODY(NK - 1, 3, 0, 0, VM0);  // tile 63

  // ---- epilogue: per lane, 4 nf-fragments = the 4 gates of one unit u ----
  const int u = bn * 64 + wc * 16 + lrow;
  const float fb = bf_[u], ib = bi_[u], cb = bc_[u], ob = bo_[u];
  const int rbase = m0 + wr * 128 + (lane >> 4) * 4;
#pragma unroll
  for (int mi = 0; mi < 8; ++mi) {
#pragma unroll
    for (int j = 0; j < 4; ++j) {
      const int m = rbase + mi * 16 + j;
      float pf = acc[mi][0][j] + fb;
      float pi = acc[mi][1][j] + ib;
      float pc = acc[mi][2][j] + cb;
      float po = acc[mi][3][j] + ob;
      float fg = fast_sigmoid(pf);
      float ig = fast_sigmoid(pi);
      float cc = fast_tanh(pc);
      float og = fast_sigmoid(po);
      float cold = cell[(size_t)m * UDIM + u];
      float cnew = fg * cold + ig * cc;
      out[(size_t)m * UDIM + u] = og * fast_tanh(cnew);
      out[CMOFF + (size_t)m * UDIM + u] = cnew;
    }
  }
}

extern "C" void kernel_launch(void* const* d_in, const int* in_sizes, int n_in,
                              void* d_out, int out_size, void* d_ws, size_t ws_size,
                              hipStream_t stream) {
  const float* inputs = (const float*)d_in[0];
  const float* hidden = (const float*)d_in[1];
  const float* cell = (const float*)d_in[2];
  const float* Wf = (const float*)d_in[3];
  const float* bf = (const float*)d_in[4];
  const float* Wi = (const float*)d_in[5];
  const float* bi = (const float*)d_in[6];
  const float* Wc = (const float*)d_in[7];
  const float* bc = (const float*)d_in[8];
  const float* Wo = (const float*)d_in[9];
  const float* bo = (const float*)d_in[10];
  float* out = (float*)d_out;

  unsigned short* Abf = (unsigned short*)d_ws;     // [4096][2048] bf16 = 16 MB
  unsigned short* Wt = Abf + (size_t)MDIM * KDIM;  // [4096][2048] bf16 = 16 MB

  pack_x<<<(MDIM * KDIM / 4) / 256, 256, 0, stream>>>(hidden, inputs, Abf);
  pack_w<<<dim3(KDIM / 32, UDIM / 32, 4), 256, 0, stream>>>(Wf, Wi, Wc, Wo, Wt);
  lstm_gemm<<<dim3(256), dim3(THREADS), 131072, stream>>>(Abf, Wt, bf, bi, bc, bo, cell, out);
}